// Round 3
// baseline (2974.807 us; speedup 1.0000x reference)
//
#include <hip/hip_runtime.h>

#define IN_C 300
#define OUT_C 200
#define NEG_SLOPE 0.2f
#define BM 80
#define BK 20

static inline int cdiv(long a, int b) { return (int)((a + b - 1) / b); }

// ---------------- utility ----------------
__global__ __launch_bounds__(256)
void zero_int_kernel(int* __restrict__ p, int n) {
  int i = blockIdx.x * blockDim.x + threadIdx.x;
  if (i < n) p[i] = 0;
}

__device__ __forceinline__ void edge_sd(const int* __restrict__ src,
                                        const int* __restrict__ dst,
                                        int i, int E, int& s, int& d) {
  if (i < E) { s = src[i]; d = dst[i]; } else { s = d = i - E; }
}

// ---------------- CSR build ----------------
__global__ __launch_bounds__(256)
void hist_kernel(const int* __restrict__ src, const int* __restrict__ dst,
                 int E, int ET, int* __restrict__ counts) {
  int i = blockIdx.x * blockDim.x + threadIdx.x;
  if (i >= ET) return;
  int s, d; edge_sd(src, dst, i, E, s, d);
  atomicAdd(counts + d, 1);
}

// inclusive scan, 1024 elems/block (256 thr x 4). out = rowptr+1.
__global__ __launch_bounds__(256)
void scan_a_kernel(const int* __restrict__ in, int n, int* __restrict__ out,
                   int* __restrict__ bsums) {
  __shared__ int lds[256];
  int t = threadIdx.x;
  int base = blockIdx.x * 1024 + t * 4;
  int v0 = (base + 0 < n) ? in[base + 0] : 0;
  int v1 = (base + 1 < n) ? in[base + 1] : 0;
  int v2 = (base + 2 < n) ? in[base + 2] : 0;
  int v3 = (base + 3 < n) ? in[base + 3] : 0;
  int s1 = v0 + v1, s2 = s1 + v2, s3 = s2 + v3;
  lds[t] = s3;
  __syncthreads();
  for (int o = 1; o < 256; o <<= 1) {
    int x = (t >= o) ? lds[t - o] : 0;
    __syncthreads();
    lds[t] += x;
    __syncthreads();
  }
  int pre = (t > 0) ? lds[t - 1] : 0;
  if (base + 0 < n) out[base + 0] = pre + v0;
  if (base + 1 < n) out[base + 1] = pre + s1;
  if (base + 2 < n) out[base + 2] = pre + s2;
  if (base + 3 < n) out[base + 3] = pre + s3;
  if (t == 255) bsums[blockIdx.x] = lds[255];
}

// single-block inclusive scan of block sums (nb <= 256)
__global__ __launch_bounds__(256)
void scan_b_kernel(int* __restrict__ bs, int nb) {
  __shared__ int lds[256];
  int t = threadIdx.x;
  lds[t] = (t < nb) ? bs[t] : 0;
  __syncthreads();
  for (int o = 1; o < 256; o <<= 1) {
    int x = (t >= o) ? lds[t - o] : 0;
    __syncthreads();
    lds[t] += x;
    __syncthreads();
  }
  if (t < nb) bs[t] = lds[t];
}

__global__ __launch_bounds__(256)
void scan_c_kernel(int* __restrict__ out, int n, const int* __restrict__ bs) {
  int i = blockIdx.x * blockDim.x + threadIdx.x;
  if (i >= n) return;
  int b = i >> 10;
  if (b > 0) out[i] += bs[b - 1];
}

__global__ __launch_bounds__(256)
void fill_kernel(const int* __restrict__ src, const int* __restrict__ dst,
                 int E, int ET, const int* __restrict__ rowptr,
                 int* __restrict__ cursor, int* __restrict__ csr_src) {
  int i = blockIdx.x * blockDim.x + threadIdx.x;
  if (i >= ET) return;
  int s, d; edge_sd(src, dst, i, E, s, d);
  int pos = rowptr[d] + atomicAdd(cursor + d, 1);
  csr_src[pos] = s;
}

// ---------------- dense projection (tiled) ----------------
// C[N,OUT_C] = A[N,K] @ W[K,OUT_C]. Block: BM=80 rows x 200 cols, BK=20.
// 256 threads; thread (rg,cg) = (t/50, t%50) computes 16 rows x 4 cols.
// A reads from LDS are wave-broadcast (same addr per rg group).
__global__ __launch_bounds__(256, 4)
void gemm_tiled_kernel(const float* __restrict__ A, const float* __restrict__ W,
                       float* __restrict__ C, int K) {
  __shared__ float As[BM][BK];     // 6.4 KB
  __shared__ float Ws[BK][OUT_C];  // 16 KB
  int t = threadIdx.x;
  int rg = t / 50;                 // 0..4 (t>=250: load-only helpers)
  int cg = t % 50;
  long row0 = (long)blockIdx.x * BM;

  float4 acc[16];
  #pragma unroll
  for (int i = 0; i < 16; ++i) acc[i] = make_float4(0.f, 0.f, 0.f, 0.f);

  for (int kc = 0; kc < K; kc += BK) {
    // stage A tile: 80 rows x 5 float4
    for (int idx = t; idx < BM * (BK / 4); idx += 256) {
      int r = idx / (BK / 4), c = idx % (BK / 4);
      *(float4*)&As[r][c * 4] = *(const float4*)(A + (row0 + r) * K + kc + c * 4);
    }
    // stage W tile: 20 rows x 50 float4
    for (int idx = t; idx < BK * (OUT_C / 4); idx += 256) {
      int r = idx / (OUT_C / 4), c = idx % (OUT_C / 4);
      *(float4*)&Ws[r][c * 4] = *(const float4*)(W + (long)(kc + r) * OUT_C + c * 4);
    }
    __syncthreads();
    if (rg < 5) {
      #pragma unroll
      for (int kk = 0; kk < BK; kk += 4) {
        float4 w0 = *(float4*)&Ws[kk + 0][cg * 4];
        float4 w1 = *(float4*)&Ws[kk + 1][cg * 4];
        float4 w2 = *(float4*)&Ws[kk + 2][cg * 4];
        float4 w3 = *(float4*)&Ws[kk + 3][cg * 4];
        #pragma unroll
        for (int i = 0; i < 16; ++i) {
          float4 a = *(float4*)&As[rg * 16 + i][kk];
          acc[i].x += a.x * w0.x + a.y * w1.x + a.z * w2.x + a.w * w3.x;
          acc[i].y += a.x * w0.y + a.y * w1.y + a.z * w2.y + a.w * w3.y;
          acc[i].z += a.x * w0.z + a.y * w1.z + a.z * w2.z + a.w * w3.z;
          acc[i].w += a.x * w0.w + a.y * w1.w + a.z * w2.w + a.w * w3.w;
        }
      }
    }
    __syncthreads();
  }
  if (rg < 5) {
    #pragma unroll
    for (int i = 0; i < 16; ++i)
      *(float4*)(C + (row0 + rg * 16 + i) * OUT_C + cg * 4) = acc[i];
  }
}

// One wave per node: alpha_src[n] = h[n,:].a_src ; alpha_dst[n] = h[n,:].a_dst
__global__ __launch_bounds__(256)
void alphas_kernel(const float* __restrict__ h, const float* __restrict__ a_src,
                   const float* __restrict__ a_dst, float* __restrict__ as_out,
                   float* __restrict__ ad_out, int N) {
  int wid = (int)(((long)blockIdx.x * blockDim.x + threadIdx.x) >> 6);
  int lane = threadIdx.x & 63;
  if (wid >= N) return;
  const float* row = h + (long)wid * OUT_C;
  float ss = 0.f, sd = 0.f;
  for (int c = lane; c < OUT_C; c += 64) {
    float v = row[c];
    ss += v * a_src[c];
    sd += v * a_dst[c];
  }
  for (int off = 32; off > 0; off >>= 1) {
    ss += __shfl_down(ss, off);
    sd += __shfl_down(sd, off);
  }
  if (lane == 0) { as_out[wid] = ss; ad_out[wid] = sd; }
}

// ---------------- fused segment-softmax + gather-aggregate + bias + relu ----
// One wave per destination node.
__global__ __launch_bounds__(256)
void gather_agg_kernel(const float* __restrict__ h, const float* __restrict__ asN,
                       const float* __restrict__ adN, const int* __restrict__ rowptr,
                       const int* __restrict__ csr_src, const float* __restrict__ bias,
                       float* __restrict__ out, int N) {
  int wid = (int)(((long)blockIdx.x * blockDim.x + threadIdx.x) >> 6);
  int lane = threadIdx.x & 63;
  if (wid >= N) return;
  int start = rowptr[wid], end = rowptr[wid + 1];
  float ad = adN[wid];

  // pass 1a: max over incoming edges
  float m = -1e30f;
  for (int j = start + lane; j < end; j += 64) {
    float sc = asN[csr_src[j]] + ad;
    sc = sc > 0.f ? sc : NEG_SLOPE * sc;
    m = fmaxf(m, sc);
  }
  for (int o = 32; o > 0; o >>= 1) m = fmaxf(m, __shfl_xor(m, o));
  // pass 1b: sum of exp
  float se = 0.f;
  for (int j = start + lane; j < end; j += 64) {
    float sc = asN[csr_src[j]] + ad;
    sc = sc > 0.f ? sc : NEG_SLOPE * sc;
    se += __expf(sc - m);
  }
  for (int o = 32; o > 0; o >>= 1) se += __shfl_xor(se, o);
  float inv = 1.0f / se;

  // pass 2: weighted gather-accumulate (all lanes walk edges together)
  float acc0 = 0.f, acc1 = 0.f, acc2 = 0.f, acc3 = 0.f;
  int c0 = lane, c1 = lane + 64, c2 = lane + 128, c3 = lane + 192;
  for (int j = start; j < end; ++j) {
    int s = csr_src[j];                 // broadcast read
    float sc = asN[s] + ad;
    sc = sc > 0.f ? sc : NEG_SLOPE * sc;
    float w = __expf(sc - m) * inv;
    const float* hrow = h + (long)s * OUT_C;
    acc0 += w * hrow[c0];
    acc1 += w * hrow[c1];
    acc2 += w * hrow[c2];
    if (c3 < OUT_C) acc3 += w * hrow[c3];
  }
  float* orow = out + (long)wid * OUT_C;
  orow[c0] = fmaxf(acc0 + bias[c0], 0.f);
  orow[c1] = fmaxf(acc1 + bias[c1], 0.f);
  orow[c2] = fmaxf(acc2 + bias[c2], 0.f);
  if (c3 < OUT_C) orow[c3] = fmaxf(acc3 + bias[c3], 0.f);
}

// ---------------- driver ----------------
static void run_layer(const float* xin, int K, const float* W,
                      const float* a_s, const float* a_d, const float* b,
                      const int* rowptr, const int* csr_src, int N,
                      float* hbuf, float* asN, float* adN, float* outbuf,
                      hipStream_t stream) {
  gemm_tiled_kernel<<<N / BM, 256, 0, stream>>>(xin, W, hbuf, K);
  alphas_kernel<<<cdiv((long)N * 64, 256), 256, 0, stream>>>(hbuf, a_s, a_d, asN, adN, N);
  gather_agg_kernel<<<cdiv((long)N * 64, 256), 256, 0, stream>>>(
      hbuf, asN, adN, rowptr, csr_src, b, outbuf, N);
}

extern "C" void kernel_launch(void* const* d_in, const int* in_sizes, int n_in,
                              void* d_out, int out_size, void* d_ws, size_t ws_size,
                              hipStream_t stream) {
  const float* x   = (const float*)d_in[0];
  const float* W0  = (const float*)d_in[1];
  const float* as0 = (const float*)d_in[2];
  const float* ad0 = (const float*)d_in[3];
  const float* b0  = (const float*)d_in[4];
  const float* W1  = (const float*)d_in[5];
  const float* as1 = (const float*)d_in[6];
  const float* ad1 = (const float*)d_in[7];
  const float* b1  = (const float*)d_in[8];
  const int*   ei  = (const int*)d_in[9];

  const int N  = in_sizes[0] / IN_C;
  const int E  = in_sizes[9] / 2;
  const int ET = E + N;
  const int* src = ei;
  const int* dst = ei + E;

  float* out = (float*)d_out;

  char* ws = (char*)d_ws;
  float* hbuf   = (float*)ws;                                  // N*OUT_C
  float* asN    = (float*)(ws + (size_t)N * OUT_C * 4);        // N
  float* adN    = asN + N;                                     // N
  int*   rowptr = (int*)(adN + N);                             // N+1
  int*   counts = rowptr + (N + 1);                            // N (also cursor)
  int*   bsums  = counts + N;                                  // 256
  int*   csrsrc = bsums + 256;                                 // ET

  const int nb = cdiv(N, 1024);

  // ---- one-time CSR build (shared by both layers) ----
  zero_int_kernel<<<cdiv(N, 256), 256, 0, stream>>>(counts, N);
  hist_kernel<<<cdiv(ET, 256), 256, 0, stream>>>(src, dst, E, ET, counts);
  scan_a_kernel<<<nb, 256, 0, stream>>>(counts, N, rowptr + 1, bsums);
  scan_b_kernel<<<1, 256, 0, stream>>>(bsums, nb);
  scan_c_kernel<<<cdiv(N, 256), 256, 0, stream>>>(rowptr + 1, N, bsums);
  zero_int_kernel<<<1, 256, 0, stream>>>(rowptr, 1);
  zero_int_kernel<<<cdiv(N, 256), 256, 0, stream>>>(counts, N);  // reuse as cursor
  fill_kernel<<<cdiv(ET, 256), 256, 0, stream>>>(src, dst, E, ET, rowptr, counts, csrsrc);

  // ---- layer 0: x -> out ----
  run_layer(x, IN_C, W0, as0, ad0, b0, rowptr, csrsrc, N, hbuf, asN, adN, out, stream);
  // ---- layer 1: out -> out (gemm reads out before gather_agg rewrites it) ----
  run_layer(out, OUT_C, W1, as1, ad1, b1, rowptr, csrsrc, N, hbuf, asN, adN, out, stream);
}

// Round 4
// 1361.669 us; speedup vs baseline: 2.1847x; 2.1847x over previous
//
#include <hip/hip_runtime.h>

#define IN_C 300
#define OUT_C 200
#define NEG_SLOPE 0.2f
#define BM 40
#define BK 20

static inline int cdiv(long a, int b) { return (int)((a + b - 1) / b); }

// ---------------- utility ----------------
__global__ __launch_bounds__(256)
void zero_int_kernel(int* __restrict__ p, int n) {
  int i = blockIdx.x * blockDim.x + threadIdx.x;
  if (i < n) p[i] = 0;
}

__device__ __forceinline__ void edge_sd(const int* __restrict__ src,
                                        const int* __restrict__ dst,
                                        int i, int E, int& s, int& d) {
  if (i < E) { s = src[i]; d = dst[i]; } else { s = d = i - E; }
}

// ---------------- CSR build ----------------
__global__ __launch_bounds__(256)
void hist_kernel(const int* __restrict__ src, const int* __restrict__ dst,
                 int E, int ET, int* __restrict__ counts) {
  int i = blockIdx.x * blockDim.x + threadIdx.x;
  if (i >= ET) return;
  int s, d; edge_sd(src, dst, i, E, s, d);
  atomicAdd(counts + d, 1);
}

// inclusive scan, 1024 elems/block (256 thr x 4). out = rowptr+1.
__global__ __launch_bounds__(256)
void scan_a_kernel(const int* __restrict__ in, int n, int* __restrict__ out,
                   int* __restrict__ bsums) {
  __shared__ int lds[256];
  int t = threadIdx.x;
  int base = blockIdx.x * 1024 + t * 4;
  int v0 = (base + 0 < n) ? in[base + 0] : 0;
  int v1 = (base + 1 < n) ? in[base + 1] : 0;
  int v2 = (base + 2 < n) ? in[base + 2] : 0;
  int v3 = (base + 3 < n) ? in[base + 3] : 0;
  int s1 = v0 + v1, s2 = s1 + v2, s3 = s2 + v3;
  lds[t] = s3;
  __syncthreads();
  for (int o = 1; o < 256; o <<= 1) {
    int x = (t >= o) ? lds[t - o] : 0;
    __syncthreads();
    lds[t] += x;
    __syncthreads();
  }
  int pre = (t > 0) ? lds[t - 1] : 0;
  if (base + 0 < n) out[base + 0] = pre + v0;
  if (base + 1 < n) out[base + 1] = pre + s1;
  if (base + 2 < n) out[base + 2] = pre + s2;
  if (base + 3 < n) out[base + 3] = pre + s3;
  if (t == 255) bsums[blockIdx.x] = lds[255];
}

// single-block inclusive scan of block sums (nb <= 256)
__global__ __launch_bounds__(256)
void scan_b_kernel(int* __restrict__ bs, int nb) {
  __shared__ int lds[256];
  int t = threadIdx.x;
  lds[t] = (t < nb) ? bs[t] : 0;
  __syncthreads();
  for (int o = 1; o < 256; o <<= 1) {
    int x = (t >= o) ? lds[t - o] : 0;
    __syncthreads();
    lds[t] += x;
    __syncthreads();
  }
  if (t < nb) bs[t] = lds[t];
}

__global__ __launch_bounds__(256)
void scan_c_kernel(int* __restrict__ out, int n, const int* __restrict__ bs) {
  int i = blockIdx.x * blockDim.x + threadIdx.x;
  if (i >= n) return;
  int b = i >> 10;
  if (b > 0) out[i] += bs[b - 1];
}

__global__ __launch_bounds__(256)
void fill_kernel(const int* __restrict__ src, const int* __restrict__ dst,
                 int E, int ET, const int* __restrict__ rowptr,
                 int* __restrict__ cursor, int* __restrict__ csr_src) {
  int i = blockIdx.x * blockDim.x + threadIdx.x;
  if (i >= ET) return;
  int s, d; edge_sd(src, dst, i, E, s, d);
  int pos = rowptr[d] + atomicAdd(cursor + d, 1);
  csr_src[pos] = s;
}

// ---------------- dense projection (tiled, spill-free) ----------------
// C[N,OUT_C] = A[N,K] @ W[K,OUT_C]. Block: BM=40 rows x 200 cols, BK=20.
// 256 threads; thread (rg,cg) = (t/50, t%50), rg<5 computes 8 rows x 4 cols
// (acc = 8 float4 = 32 VGPRs; R3's 16 float4 spilled to scratch -> 3 GB writes).
__global__ __launch_bounds__(256)
void gemm_tiled_kernel(const float* __restrict__ A, const float* __restrict__ W,
                       float* __restrict__ C, int K) {
  __shared__ float As[BM][BK];     // 3.2 KB
  __shared__ float Ws[BK][OUT_C];  // 16 KB
  int t = threadIdx.x;
  int rg = t / 50;                 // 0..4 compute; 5 = load-only helpers
  int cg = t % 50;
  long row0 = (long)blockIdx.x * BM;

  float4 acc[8];
  #pragma unroll
  for (int i = 0; i < 8; ++i) acc[i] = make_float4(0.f, 0.f, 0.f, 0.f);

  for (int kc = 0; kc < K; kc += BK) {
    // stage A tile: 40 rows x 5 float4 (200 float4s, one pass)
    if (t < BM * (BK / 4)) {
      int r = t / (BK / 4), c = t % (BK / 4);
      *(float4*)&As[r][c * 4] = *(const float4*)(A + (row0 + r) * K + kc + c * 4);
    }
    // stage W tile: 20 rows x 50 float4
    for (int idx = t; idx < BK * (OUT_C / 4); idx += 256) {
      int r = idx / (OUT_C / 4), c = idx % (OUT_C / 4);
      *(float4*)&Ws[r][c * 4] = *(const float4*)(W + (long)(kc + r) * OUT_C + c * 4);
    }
    __syncthreads();
    if (rg < 5) {
      #pragma unroll
      for (int kk = 0; kk < BK; kk += 4) {
        float4 w0 = *(float4*)&Ws[kk + 0][cg * 4];
        float4 w1 = *(float4*)&Ws[kk + 1][cg * 4];
        float4 w2 = *(float4*)&Ws[kk + 2][cg * 4];
        float4 w3 = *(float4*)&Ws[kk + 3][cg * 4];
        #pragma unroll
        for (int i = 0; i < 8; ++i) {
          float4 a = *(float4*)&As[rg * 8 + i][kk];  // wave-broadcast
          acc[i].x += a.x * w0.x + a.y * w1.x + a.z * w2.x + a.w * w3.x;
          acc[i].y += a.x * w0.y + a.y * w1.y + a.z * w2.y + a.w * w3.y;
          acc[i].z += a.x * w0.z + a.y * w1.z + a.z * w2.z + a.w * w3.z;
          acc[i].w += a.x * w0.w + a.y * w1.w + a.z * w2.w + a.w * w3.w;
        }
      }
    }
    __syncthreads();
  }
  if (rg < 5) {
    #pragma unroll
    for (int i = 0; i < 8; ++i)
      *(float4*)(C + (row0 + rg * 8 + i) * OUT_C + cg * 4) = acc[i];
  }
}

// One wave per node: alpha_src[n] = h[n,:].a_src ; alpha_dst[n] = h[n,:].a_dst
__global__ __launch_bounds__(256)
void alphas_kernel(const float* __restrict__ h, const float* __restrict__ a_src,
                   const float* __restrict__ a_dst, float* __restrict__ as_out,
                   float* __restrict__ ad_out, int N) {
  int wid = (int)(((long)blockIdx.x * blockDim.x + threadIdx.x) >> 6);
  int lane = threadIdx.x & 63;
  if (wid >= N) return;
  const float* row = h + (long)wid * OUT_C;
  float ss = 0.f, sd = 0.f;
  for (int c = lane; c < OUT_C; c += 64) {
    float v = row[c];
    ss += v * a_src[c];
    sd += v * a_dst[c];
  }
  for (int off = 32; off > 0; off >>= 1) {
    ss += __shfl_down(ss, off);
    sd += __shfl_down(sd, off);
  }
  if (lane == 0) { as_out[wid] = ss; ad_out[wid] = sd; }
}

// ---------------- fused segment-softmax + gather-aggregate + bias + relu ----
// One wave per destination node.
__global__ __launch_bounds__(256)
void gather_agg_kernel(const float* __restrict__ h, const float* __restrict__ asN,
                       const float* __restrict__ adN, const int* __restrict__ rowptr,
                       const int* __restrict__ csr_src, const float* __restrict__ bias,
                       float* __restrict__ out, int N) {
  int wid = (int)(((long)blockIdx.x * blockDim.x + threadIdx.x) >> 6);
  int lane = threadIdx.x & 63;
  if (wid >= N) return;
  int start = rowptr[wid], end = rowptr[wid + 1];
  float ad = adN[wid];

  // pass 1a: max over incoming edges
  float m = -1e30f;
  for (int j = start + lane; j < end; j += 64) {
    float sc = asN[csr_src[j]] + ad;
    sc = sc > 0.f ? sc : NEG_SLOPE * sc;
    m = fmaxf(m, sc);
  }
  for (int o = 32; o > 0; o >>= 1) m = fmaxf(m, __shfl_xor(m, o));
  // pass 1b: sum of exp
  float se = 0.f;
  for (int j = start + lane; j < end; j += 64) {
    float sc = asN[csr_src[j]] + ad;
    sc = sc > 0.f ? sc : NEG_SLOPE * sc;
    se += __expf(sc - m);
  }
  for (int o = 32; o > 0; o >>= 1) se += __shfl_xor(se, o);
  float inv = 1.0f / se;

  // pass 2: weighted gather-accumulate (all lanes walk edges together)
  float acc0 = 0.f, acc1 = 0.f, acc2 = 0.f, acc3 = 0.f;
  int c0 = lane, c1 = lane + 64, c2 = lane + 128, c3 = lane + 192;
  for (int j = start; j < end; ++j) {
    int s = csr_src[j];                 // broadcast read
    float sc = asN[s] + ad;
    sc = sc > 0.f ? sc : NEG_SLOPE * sc;
    float w = __expf(sc - m) * inv;
    const float* hrow = h + (long)s * OUT_C;
    acc0 += w * hrow[c0];
    acc1 += w * hrow[c1];
    acc2 += w * hrow[c2];
    if (c3 < OUT_C) acc3 += w * hrow[c3];
  }
  float* orow = out + (long)wid * OUT_C;
  orow[c0] = fmaxf(acc0 + bias[c0], 0.f);
  orow[c1] = fmaxf(acc1 + bias[c1], 0.f);
  orow[c2] = fmaxf(acc2 + bias[c2], 0.f);
  if (c3 < OUT_C) orow[c3] = fmaxf(acc3 + bias[c3], 0.f);
}

// ---------------- driver ----------------
static void run_layer(const float* xin, int K, const float* W,
                      const float* a_s, const float* a_d, const float* b,
                      const int* rowptr, const int* csr_src, int N,
                      float* hbuf, float* asN, float* adN, float* outbuf,
                      hipStream_t stream) {
  gemm_tiled_kernel<<<N / BM, 256, 0, stream>>>(xin, W, hbuf, K);
  alphas_kernel<<<cdiv((long)N * 64, 256), 256, 0, stream>>>(hbuf, a_s, a_d, asN, adN, N);
  gather_agg_kernel<<<cdiv((long)N * 64, 256), 256, 0, stream>>>(
      hbuf, asN, adN, rowptr, csr_src, b, outbuf, N);
}

extern "C" void kernel_launch(void* const* d_in, const int* in_sizes, int n_in,
                              void* d_out, int out_size, void* d_ws, size_t ws_size,
                              hipStream_t stream) {
  const float* x   = (const float*)d_in[0];
  const float* W0  = (const float*)d_in[1];
  const float* as0 = (const float*)d_in[2];
  const float* ad0 = (const float*)d_in[3];
  const float* b0  = (const float*)d_in[4];
  const float* W1  = (const float*)d_in[5];
  const float* as1 = (const float*)d_in[6];
  const float* ad1 = (const float*)d_in[7];
  const float* b1  = (const float*)d_in[8];
  const int*   ei  = (const int*)d_in[9];

  const int N  = in_sizes[0] / IN_C;
  const int E  = in_sizes[9] / 2;
  const int ET = E + N;
  const int* src = ei;
  const int* dst = ei + E;

  float* out = (float*)d_out;

  char* ws = (char*)d_ws;
  float* hbuf   = (float*)ws;                                  // N*OUT_C
  float* asN    = (float*)(ws + (size_t)N * OUT_C * 4);        // N
  float* adN    = asN + N;                                     // N
  int*   rowptr = (int*)(adN + N);                             // N+1
  int*   counts = rowptr + (N + 1);                            // N (also cursor)
  int*   bsums  = counts + N;                                  // 256
  int*   csrsrc = bsums + 256;                                 // ET

  const int nb = cdiv(N, 1024);

  // ---- one-time CSR build (shared by both layers) ----
  zero_int_kernel<<<cdiv(N, 256), 256, 0, stream>>>(counts, N);
  hist_kernel<<<cdiv(ET, 256), 256, 0, stream>>>(src, dst, E, ET, counts);
  scan_a_kernel<<<nb, 256, 0, stream>>>(counts, N, rowptr + 1, bsums);
  scan_b_kernel<<<1, 256, 0, stream>>>(bsums, nb);
  scan_c_kernel<<<cdiv(N, 256), 256, 0, stream>>>(rowptr + 1, N, bsums);
  zero_int_kernel<<<1, 256, 0, stream>>>(rowptr, 1);
  zero_int_kernel<<<cdiv(N, 256), 256, 0, stream>>>(counts, N);  // reuse as cursor
  fill_kernel<<<cdiv(ET, 256), 256, 0, stream>>>(src, dst, E, ET, rowptr, counts, csrsrc);

  // ---- layer 0: x -> out ----
  run_layer(x, IN_C, W0, as0, ad0, b0, rowptr, csrsrc, N, hbuf, asN, adN, out, stream);
  // ---- layer 1: out -> out (gemm reads out before gather_agg rewrites it) ----
  run_layer(out, OUT_C, W1, as1, ad1, b1, rowptr, csrsrc, N, hbuf, asN, adN, out, stream);
}